// Round 4
// baseline (3273.391 us; speedup 1.0000x reference)
//
#include <hip/hip_runtime.h>

#define TT 256         // time steps
#define VV 5000        // vocab
#define NC4 1250       // VV/4 float4 chunks per row
#define BEAMW 16
#define WASR 0.7f
#define WLM 0.3f
#define SOS_TOK 1
#define CAP 512
#define LK 256         // stored (sorted) list length
#define LTGT 200       // histogram cumulative target
#define WIN 128        // evaluated window per list
#define SA (WIN + 4)   // staged A-list entries (need index WIN)

// ws float offsets
#define OFF_LSTAT4 0                     // float4[VV]: {m, logS, cutv, cuttok_bits}
#define OFF_AM     (4*VV)                // [TT]
#define OFF_ALS    (4*VV + TT)           // [TT]
#define OFF_ABND   (4*VV + 2*TT)         // [TT]  theta-bound (scaled) for asr rows
#define OFF_LBND   (4*VV + 3*TT)         // [VV]  theta-bound (scaled) for lm rows
#define OFF_LISTS  (4*VV + 3*TT + VV)    // float2 L[VV][LK] then A[TT][LK]

static inline size_t ws_need_floats() {
  return (size_t)OFF_LISTS + 2ull * (VV + TT) * LK;
}

// ---------------- prep: row stats + sorted shortlists ----------
__global__ __launch_bounds__(256) void prep_kernel(
    const float* __restrict__ asr, const float* __restrict__ lm,
    float* __restrict__ ws, int build)
{
  __shared__ float sm[8];
  __shared__ int   hist[256];
  __shared__ float s_theta;
  __shared__ int   s_cnt;
  __shared__ float s_sv[LK];
  __shared__ int   s_tk[LK];
  __shared__ float s_sv2[LK];
  __shared__ int   s_tk2[LK];

  const int row = blockIdx.x;
  const bool is_lm = (row < VV);
  const int t = row - VV;
  const float* src = is_lm ? (lm + (size_t)row * VV) : (asr + (size_t)t * VV);
  const float4* s4 = (const float4*)src;
  const int tid = (int)threadIdx.x;

  float4 x[5];
  float m = -INFINITY;
#pragma unroll
  for (int k = 0; k < 5; ++k) {
    int c = tid + 256 * k;
    if (c < NC4) {
      x[k] = s4[c];
      m = fmaxf(m, fmaxf(fmaxf(x[k].x, x[k].y), fmaxf(x[k].z, x[k].w)));
    }
  }
#pragma unroll
  for (int j = 1; j < 64; j <<= 1) m = fmaxf(m, __shfl_xor(m, j, 64));
  if ((tid & 63) == 0) sm[tid >> 6] = m;
  __syncthreads();
  m = fmaxf(fmaxf(sm[0], sm[1]), fmaxf(sm[2], sm[3]));
  __syncthreads();

  float ssum = 0.f;
#pragma unroll
  for (int k = 0; k < 5; ++k) {
    int c = tid + 256 * k;
    if (c < NC4) {
      ssum += expf(x[k].x - m);
      ssum += expf(x[k].y - m);
      ssum += expf(x[k].z - m);
      ssum += expf(x[k].w - m);
    }
  }
#pragma unroll
  for (int j = 1; j < 64; j <<= 1) ssum += __shfl_xor(ssum, j, 64);
  if ((tid & 63) == 0) sm[4 + (tid >> 6)] = ssum;
  __syncthreads();
  ssum = (sm[4] + sm[5]) + (sm[6] + sm[7]);
  const float logS = logf(ssum);

  if (!build) {
    if (tid == 0) {
      if (is_lm) ((float4*)(ws + OFF_LSTAT4))[row] = make_float4(m, logS, 0.f, 0.f);
      else { ws[OFF_AM + t] = m; ws[OFF_ALS + t] = logS; }
    }
    return;
  }
  if (tid == 0 && !is_lm) { ws[OFF_AM + t] = m; ws[OFF_ALS + t] = logS; }

  // histogram of y = m - x, 256 bins of width 1/16
  hist[tid] = 0;
  __syncthreads();
#pragma unroll
  for (int k = 0; k < 5; ++k) {
    int c = tid + 256 * k;
    if (c < NC4) {
      float vv[4] = {x[k].x, x[k].y, x[k].z, x[k].w};
#pragma unroll
      for (int j = 0; j < 4; ++j) {
        float y = m - vv[j];
        int b = (int)(y * 16.0f);
        b = b < 0 ? 0 : (b > 255 ? 255 : b);
        atomicAdd(&hist[b], 1);
      }
    }
  }
  __syncthreads();
  if (tid == 0) {
    int c = 0, b = 0;
    for (; b < 255; ++b) { c += hist[b]; if (c >= LTGT) break; }
    s_theta = m - (float)(b + 1) * 0.0625f;
    s_cnt = 0;
  }
  __syncthreads();
  const float theta = s_theta;
  const float wgt = is_lm ? WLM : WASR;

  // collect entries >= theta
#pragma unroll
  for (int k = 0; k < 5; ++k) {
    int c = tid + 256 * k;
    if (c < NC4) {
      float vv[4] = {x[k].x, x[k].y, x[k].z, x[k].w};
#pragma unroll
      for (int j = 0; j < 4; ++j) {
        float xv = vv[j];
        if (xv >= theta) {
          int p = atomicAdd(&s_cnt, 1);
          if (p < LK) {
            float sv = __fmul_rn(wgt, __fsub_rn(__fsub_rn(xv, m), logS));
            s_sv[p] = sv; s_tk[p] = c * 4 + j;
          }
        }
      }
    }
  }
  __syncthreads();
  const int cnt = s_cnt;
  const bool ovf = (cnt > LK);
  const int nv = ovf ? 0 : cnt;

  // rank-sort (sv desc, tok asc)
  if (tid < nv) {
    float v = s_sv[tid]; int tk = s_tk[tid];
    int r = 0;
    for (int j = 0; j < nv; ++j) {
      float vj = s_sv[j];
      r += ((vj > v) || (vj == v && s_tk[j] < tk)) ? 1 : 0;
    }
    s_sv2[r] = v; s_tk2[r] = tk;
  }
  __syncthreads();

  float2* Llists = (float2*)(ws + OFF_LISTS);
  float2* dst = is_lm ? (Llists + (size_t)row * LK)
                      : (Llists + (size_t)VV * LK + (size_t)t * LK);
  for (int p = tid; p < LK; p += 256)
    dst[p] = (p < nv) ? make_float2(s_sv2[p], __int_as_float(s_tk2[p]))
                      : make_float2(-1e30f, __int_as_float(0x7FFFFFFF));

  if (tid == 0) {
    float svth = __fmul_rn(wgt, __fsub_rn(__fsub_rn(theta, m), logS));
    float bnd = ovf ? INFINITY : svth;
    float cutv; int cutt;
    if (ovf)           { cutv = INFINITY; cutt = -2; }          // in-window test always false
    else if (nv > WIN) { cutv = s_sv2[WIN - 1]; cutt = s_tk2[WIN - 1]; }  // lex cut on sv
    else               { cutv = theta; cutt = 0x7FFFFFFF; }     // whole-list mode, raw compare
    if (is_lm) {
      ((float4*)(ws + OFF_LSTAT4))[row] = make_float4(m, logS, cutv, __int_as_float(cutt));
      ws[OFF_LBND + row] = bnd;
    } else {
      ws[OFF_ABND + t] = bnd;
    }
  }
}

// ---------------- helpers ----------------
__device__ __forceinline__ float bitonic64_desc_val(float v, int lane) {
#pragma unroll
  for (int kk = 2; kk <= 64; kk <<= 1)
#pragma unroll
    for (int j = kk >> 1; j > 0; j >>= 1) {
      float o = __shfl_xor(v, j, 64);
      bool keepMax = (((lane & kk) == 0) == ((lane & j) == 0));
      v = keepMax ? fmaxf(v, o) : fminf(v, o);
    }
  return v;
}

__device__ __forceinline__ void bitonic64_desc_pair(float& bv, int& bi, int lane) {
#pragma unroll
  for (int kk = 2; kk <= 64; kk <<= 1)
#pragma unroll
    for (int j = kk >> 1; j > 0; j >>= 1) {
      float ov = __shfl_xor(bv, j, 64);
      int   oi = __shfl_xor(bi, j, 64);
      bool keepTop = (((lane & kk) == 0) == ((lane & j) == 0));
      bool mineBetter = (bv > ov) || (bv == ov && bi < oi);
      if (keepTop != mineBetter) { bv = ov; bi = oi; }
    }
}

__device__ __forceinline__ float cand_val(float s, float a, float am, float als,
                                          float x, float mB, float lsB) {
  float av = __fmul_rn(WASR, __fsub_rn(__fsub_rn(a, am), als));
  float lv = __fmul_rn(WLM,  __fsub_rn(__fsub_rn(x, mB), lsB));
  return __fadd_rn(__fadd_rn(s, av), lv);
}

// ---------------- fast beam kernel: sorted-window candidates + joint bound ----
__global__ __launch_bounds__(1024, 4) void beam_fast(
    const float* __restrict__ asr, const float* __restrict__ lm,
    const float* __restrict__ ws, float* __restrict__ out)
{
  __shared__ float2 s_alist[2][SA];
  __shared__ float  s_scores[BEAMW];
  __shared__ int    s_last[BEAMW];
  __shared__ float4 s_lstat[BEAMW];       // {m, logS, cutv, cuttok}
  __shared__ float  s_lbnd16[BEAMW];
  __shared__ float  s_am[TT], s_als[TT], s_abnd[TT];
  __shared__ float  s_lmax[1024];
  __shared__ float  s_tau[BEAMW];
  __shared__ float  s_bound[BEAMW];
  __shared__ float  s_m2v[64];
  __shared__ int    s_m2i[64];
  __shared__ float  s_bufval[CAP];
  __shared__ int    s_bufidx[CAP];
  __shared__ int    s_cnt;
  __shared__ int    s_flags;
  __shared__ float  s_selv[BEAMW];
  __shared__ int    s_seli[BEAMW];
  __shared__ float  s_tau16;
  __shared__ unsigned short s_toks[TT * BEAMW];
  __shared__ unsigned char  s_bps[TT * BEAMW];

  const int tid = (int)threadIdx.x;
  const int lane = tid & 63;
  const int w = tid >> 6;
  const float2* __restrict__ Llists = (const float2*)(ws + OFF_LISTS);
  const float2* __restrict__ Alists = Llists + (size_t)VV * LK;
  const float4* __restrict__ lstat4 = (const float4*)(ws + OFF_LSTAT4);

  if (tid < TT) {
    s_am[tid]   = ws[OFF_AM + tid];
    s_als[tid]  = ws[OFF_ALS + tid];
    s_abnd[tid] = ws[OFF_ABND + tid];
  }
  if (tid < BEAMW) {
    s_scores[tid] = (tid == 0) ? 0.0f : -1e30f;
    s_last[tid]   = SOS_TOK;
    s_lstat[tid]  = lstat4[SOS_TOK];
    s_lbnd16[tid] = ws[OFF_LBND + SOS_TOK];
  }
  if (tid < SA) s_alist[0][tid] = Alists[tid];
  if (tid == 0) { s_cnt = 0; s_flags = 0; }
  __syncthreads();
  int cur = 0;

  // wave0: rank-select top-16 from (sva,sia)[0..nn), publish selv/seli/tau16
  auto rank_sel = [&](const float* sva, const int* sia, int nn) {
    float bv = (lane < nn) ? sva[lane] : -INFINITY;
    int   bi = (lane < nn) ? sia[lane] : 0x7FFFFFFF;
    int r = 0;
#pragma unroll 4
    for (int j = 0; j < nn; ++j) {
      float vj = sva[j]; int ij = sia[j];
      r += ((vj > bv) || (vj == bv && ij < bi)) ? 1 : 0;
    }
    if (lane < nn && r < BEAMW) {
      s_selv[r] = bv; s_seli[r] = bi;
      if (r == BEAMW - 1) s_tau16 = bv;
    }
  };
  // wave0: commit from selv/seli (state + history)
  auto commit_only = [&](int t_) {
    if (lane < BEAMW) {
      float val = s_selv[lane]; int flat = s_seli[lane];
      int bb = flat / VV; int tk = flat - bb * VV;
      float4 st = lstat4[tk];
      float lb = ws[OFF_LBND + tk];
      s_scores[lane] = val; s_last[lane] = tk;
      s_lstat[lane] = st;  s_lbnd16[lane] = lb;
      s_toks[t_ * BEAMW + lane] = (unsigned short)tk;
      s_bps[t_ * BEAMW + lane]  = (unsigned char)bb;
    }
  };
  // waves 0-3: per-64-segment rank-select into s_m2 (64 < nn <= 256)
  auto seg_phase = [&](int nn) {
    if (w < 4) {
      int base = w << 6;
      int lim = nn - base; lim = lim < 0 ? 0 : (lim > 64 ? 64 : lim);
      float bv = (lane < lim) ? s_bufval[base + lane] : -INFINITY;
      int   bi = (lane < lim) ? s_bufidx[base + lane] : 0x7FFFFFFF;
      int r = 0;
#pragma unroll 4
      for (int j = 0; j < lim; ++j) {
        float vj = s_bufval[base + j]; int ij = s_bufidx[base + j];
        r += ((vj > bv) || (vj == bv && ij < bi)) ? 1 : 0;
      }
      if (lane < lim && r < BEAMW) { s_m2v[(w << 4) | r] = bv; s_m2i[(w << 4) | r] = bi; }
      if (lane >= lim && lane < BEAMW) { s_m2v[(w << 4) | lane] = -INFINITY; s_m2i[(w << 4) | lane] = 0x7FFFFFFF; }
    }
  };

  for (int t = 0; t < TT; ++t) {
    const float s = s_scores[w];
    const int last = s_last[w];
    const float4 st = s_lstat[w];
    const float mB = st.x, lsB = st.y, Lrc = st.z;
    const int Lct = __float_as_int(st.w);
    const float lbnd = s_lbnd16[w];
    const float am = s_am[t], als = s_als[t];
    const float2* __restrict__ Ll = Llists + (size_t)last * LK;

    // loads (L-list global first: longest chain Ll -> asr gather)
    float2 le0 = Ll[lane];
    float2 le1 = Ll[64 + lane];
    float2 lext = Ll[WIN];
    float2 ae0 = s_alist[cur][lane];
    float2 ae1 = s_alist[cur][64 + lane];
    float2 aext = s_alist[cur][WIN];

    if (lane == 0)
      s_bound[w] = s + fmaxf(aext.x, s_abnd[t]) + fmaxf(lext.x, lbnd) + 1e-3f;

    auto a_side = [&](float2 ae) -> float {
      bool valid = ae.x > -9e29f;
      int tk = __float_as_int(ae.y);
      int ck = valid ? tk : 0;
      float xr = lm[(size_t)last * VV + ck];
      float svr = __fmul_rn(WLM, __fsub_rn(__fsub_rn(xr, mB), lsB));
      bool inL = (Lct == 0x7FFFFFFF) ? (xr >= Lrc)
               : ((svr > Lrc) || (svr == Lrc && tk <= Lct));
      return (valid && !inL) ? __fadd_rn(__fadd_rn(s, ae.x), svr) : -INFINITY;
    };
    auto l_side = [&](float2 le) -> float {
      bool valid = le.x > -9e29f;
      int tk = __float_as_int(le.y);
      int ck = valid ? tk : 0;
      float ar = asr[(size_t)t * VV + ck];
      float avr = __fmul_rn(WASR, __fsub_rn(__fsub_rn(ar, am), als));
      return valid ? __fadd_rn(__fadd_rn(s, avr), le.x) : -INFINITY;
    };

    float cv[4]; int ct[4];
    cv[0] = a_side(ae0); ct[0] = __float_as_int(ae0.y);
    cv[1] = a_side(ae1); ct[1] = __float_as_int(ae1.y);
    cv[2] = l_side(le0); ct[2] = __float_as_int(le0.y);
    cv[3] = l_side(le1); ct[3] = __float_as_int(le1.y);

    // per-wave 16th-largest lane-max -> s_tau[w]
    float m4 = fmaxf(fmaxf(cv[0], cv[1]), fmaxf(cv[2], cv[3]));
    float vs = bitonic64_desc_val(m4, lane);
    if (lane == 15) s_tau[w] = vs;
    __syncthreads();                                   // A

    float tg = s_tau[0];
#pragma unroll
    for (int b = 1; b < BEAMW; ++b) tg = fmaxf(tg, s_tau[b]);

#pragma unroll
    for (int k = 0; k < 4; ++k) {
      if (cv[k] >= tg) {
        int p = atomicAdd(&s_cnt, 1);
        if (p < CAP) { s_bufval[p] = cv[k]; s_bufidx[p] = w * VV + ct[k]; }
      }
    }
    __syncthreads();                                   // B

    int n = s_cnt;
    bool redo = (n > 256);

    if (!redo) {
      if (n > 64) seg_phase(n);
      __syncthreads();                                 // C1
      if (w == 0) {
        if (n <= 64) rank_sel(s_bufval, s_bufidx, n);
        else         rank_sel(s_m2v, s_m2i, 64);
        commit_only(t);
        float t16 = s_tau16;
        unsigned long long mk = __ballot(lane < BEAMW && (s_bound[lane] > t16));
        if (lane == 0) s_flags = (int)(mk & 0xFFFFull);
      }
      if (tid >= 512 && tid < 512 + SA) {
        int tn = (t + 1 < TT) ? (t + 1) : t;
        s_alist[cur ^ 1][tid - 512] = Alists[(size_t)tn * LK + (tid - 512)];
      }
      if (tid == 64) s_cnt = 0;
      __syncthreads();                                 // C2
      redo = (s_flags != 0);
    }

    if (redo) {
      // exact full scan of all 16 rows (self-contained; uses loop-top registers)
      if (tid == 0) s_cnt = 0;
      const float4* A4p = (const float4*)(asr + (size_t)t * VV);
      const float4* L4p = (const float4*)(lm + (size_t)last * VV);
      float chm[20]; float rowm = -INFINITY;
#pragma unroll
      for (int k = 0; k < 20; ++k) {
        int c = lane + (k << 6);
        bool ok = (c < NC4);
        int cc = ok ? c : 0;
        float4 a4 = A4p[cc]; float4 l4 = L4p[cc];
        float vx = cand_val(s, a4.x, am, als, l4.x, mB, lsB);
        float vy = cand_val(s, a4.y, am, als, l4.y, mB, lsB);
        float vz = cand_val(s, a4.z, am, als, l4.z, mB, lsB);
        float vw = cand_val(s, a4.w, am, als, l4.w, mB, lsB);
        float cm = fmaxf(fmaxf(vx, vy), fmaxf(vz, vw));
        if (!ok) cm = -INFINITY;
        chm[k] = cm; rowm = fmaxf(rowm, cm);
      }
      float vsr = bitonic64_desc_val(rowm, lane);
      if (lane == 15) s_tau[w] = vsr;
      __syncthreads();
      float tg2 = s_tau[0];
#pragma unroll
      for (int b = 1; b < BEAMW; ++b) tg2 = fmaxf(tg2, s_tau[b]);
#pragma unroll
      for (int k = 0; k < 20; ++k) {
        if (chm[k] >= tg2) {
          int c = lane + (k << 6);
          float4 a4 = A4p[c]; float4 l4 = L4p[c];
          float ar4[4] = {a4.x, a4.y, a4.z, a4.w};
          float lr4[4] = {l4.x, l4.y, l4.z, l4.w};
#pragma unroll
          for (int i = 0; i < 4; ++i) {
            float v = cand_val(s, ar4[i], am, als, lr4[i], mB, lsB);
            if (v >= tg2) {
              int p = atomicAdd(&s_cnt, 1);
              if (p < CAP) { s_bufval[p] = v; s_bufidx[p] = w * VV + c * 4 + i; }
            }
          }
        }
      }
      __syncthreads();
      int n2 = s_cnt; if (n2 > CAP) n2 = CAP;
      if (n2 > 64 && n2 <= 256) seg_phase(n2);
      if (n2 > 256 && w == 0) {
        // iterative exact extraction (rare)
        float pv = -INFINITY; int pi = 0x7FFFFFFF;
        for (int it = 0; it < BEAMW; ++it) {
          float cvv = -INFINITY; int cii = 0x7FFFFFFF;
          for (int k2 = 0; k2 < CAP / 64; ++k2) {
            int p = lane + (k2 << 6);
            if (p < n2) {
              float vv2 = s_bufval[p]; int ii2 = s_bufidx[p];
              bool lessPrev = (it == 0) || (vv2 < pv) || (vv2 == pv && ii2 > pi);
              bool better = (vv2 > cvv) || (vv2 == cvv && ii2 < cii);
              if (lessPrev && better) { cvv = vv2; cii = ii2; }
            }
          }
          for (int j = 1; j < 64; j <<= 1) {
            float ov = __shfl_xor(cvv, j, 64); int oi = __shfl_xor(cii, j, 64);
            bool ob = (ov > cvv) || (ov == cvv && oi < cii);
            if (ob) { cvv = ov; cii = oi; }
          }
          if (lane == 0) { s_selv[it] = cvv; s_seli[it] = cii; }
          pv = cvv; pi = cii;
        }
      }
      __syncthreads();
      if (w == 0) {
        if (n2 <= 64)       rank_sel(s_bufval, s_bufidx, n2);
        else if (n2 <= 256) rank_sel(s_m2v, s_m2i, 64);
        commit_only(t);
      }
      if (tid >= 512 && tid < 512 + SA) {
        int tn = (t + 1 < TT) ? (t + 1) : t;
        s_alist[cur ^ 1][tid - 512] = Alists[(size_t)tn * LK + (tid - 512)];
      }
      if (tid == 64) s_cnt = 0;
      __syncthreads();                                 // D
    }
    cur ^= 1;
  }

  if (tid < BEAMW) {
    out[tid] = s_scores[tid];
    int ptr = tid;
    for (int t = TT - 1; t >= 0; --t) {
      int tok = (int)s_toks[t * BEAMW + ptr];
      out[BEAMW + tid * TT + t] = (float)tok;
      ptr = (int)s_bps[t * BEAMW + ptr];
    }
  }
}

// ---------------- fallback: full-scan kernel (ws too small for lists) ----
__global__ __launch_bounds__(1024, 4) void beam_slow(
    const float* __restrict__ asr, const float* __restrict__ lm,
    const float* __restrict__ ws, float* __restrict__ out)
{
  __shared__ float s_scores[BEAMW];
  __shared__ int   s_last[BEAMW];
  __shared__ float s_lmm[BEAMW], s_lmls[BEAMW];
  __shared__ float s_tau[BEAMW];
  __shared__ float s_bufval[CAP];
  __shared__ int   s_bufidx[CAP];
  __shared__ int   s_cnt;
  __shared__ unsigned short s_toks[TT * BEAMW];
  __shared__ unsigned char  s_bps[TT * BEAMW];

  const int tid = (int)threadIdx.x;
  const int lane = tid & 63;
  const int w = tid >> 6;
  const float4* __restrict__ lstat4 = (const float4*)(ws + OFF_LSTAT4);

  if (tid < BEAMW) {
    s_scores[tid] = (tid == 0) ? 0.0f : -1e30f;
    s_last[tid] = SOS_TOK;
    float4 st = lstat4[SOS_TOK];
    s_lmm[tid] = st.x; s_lmls[tid] = st.y;
  }
  if (tid == 0) s_cnt = 0;
  __syncthreads();

  for (int t = 0; t < TT; ++t) {
    const float s = s_scores[w];
    const float mB = s_lmm[w], lsB = s_lmls[w];
    const int lastb = s_last[w];
    const float am = ws[OFF_AM + t], als = ws[OFF_ALS + t];
    const float4* __restrict__ L4p = (const float4*)(lm + (size_t)lastb * VV);
    const float4* __restrict__ A4p = (const float4*)(asr + (size_t)t * VV);

    float chm[20]; float rowm = -INFINITY;
#pragma unroll
    for (int k = 0; k < 20; ++k) {
      int c = lane + 64 * k;
      bool ok = (c < NC4);
      int cc = ok ? c : 0;
      float4 A4 = A4p[cc]; float4 L4 = L4p[cc];
      float vx = cand_val(s, A4.x, am, als, L4.x, mB, lsB);
      float vy = cand_val(s, A4.y, am, als, L4.y, mB, lsB);
      float vz = cand_val(s, A4.z, am, als, L4.z, mB, lsB);
      float vw = cand_val(s, A4.w, am, als, L4.w, mB, lsB);
      float cm = fmaxf(fmaxf(vx, vy), fmaxf(vz, vw));
      if (!ok) cm = -INFINITY;
      chm[k] = cm; rowm = fmaxf(rowm, cm);
    }
    {
      float v = bitonic64_desc_val(rowm, lane);
      if (lane == 15) s_tau[w] = v;
    }
    if (tid == 0) s_cnt = 0;
    __syncthreads();

    float tg = s_tau[lane & 15];
#pragma unroll
    for (int j = 1; j <= 8; j <<= 1) tg = fmaxf(tg, __shfl_xor(tg, j, 64));

#pragma unroll
    for (int k = 0; k < 20; ++k) {
      if (chm[k] >= tg) {
        int c = lane + 64 * k;
        float4 A4 = A4p[c]; float4 L4 = L4p[c];
        float ar4[4] = {A4.x, A4.y, A4.z, A4.w};
        float lr4[4] = {L4.x, L4.y, L4.z, L4.w};
#pragma unroll
        for (int i = 0; i < 4; ++i) {
          float v = cand_val(s, ar4[i], am, als, lr4[i], mB, lsB);
          if (v >= tg) {
            int p = atomicAdd(&s_cnt, 1);
            if (p < CAP) { s_bufval[p] = v; s_bufidx[p] = w * VV + c * 4 + i; }
          }
        }
      }
    }
    __syncthreads();

    if (w == 0) {
      int n = s_cnt; if (n > CAP) n = CAP;
      if (n <= 64) {
        float bv = (lane < n) ? s_bufval[lane] : -INFINITY;
        int   bi = (lane < n) ? s_bufidx[lane] : 0x7FFFFFFF;
        bitonic64_desc_pair(bv, bi, lane);
        if (lane < BEAMW) {
          int flat = bi;
          int bb = flat / VV; int tok = flat - bb * VV;
          float4 st = lstat4[tok];
          s_scores[lane] = bv; s_last[lane] = tok;
          s_lmm[lane] = st.x; s_lmls[lane] = st.y;
          s_toks[t * BEAMW + lane] = (unsigned short)tok;
          s_bps[t * BEAMW + lane] = (unsigned char)bb;
        }
      } else {
        float pv = -INFINITY; int pi = 0x7FFFFFFF;
        for (int it = 0; it < BEAMW; ++it) {
          float cvv = -INFINITY; int cii = 0x7FFFFFFF;
          for (int k2 = 0; k2 < CAP / 64; ++k2) {
            int p = lane + 64 * k2;
            if (p < n) {
              float vv2 = s_bufval[p]; int ii2 = s_bufidx[p];
              bool lessPrev = (it == 0) || (vv2 < pv) || (vv2 == pv && ii2 > pi);
              bool better = (vv2 > cvv) || (vv2 == cvv && ii2 < cii);
              if (lessPrev && better) { cvv = vv2; cii = ii2; }
            }
          }
          for (int j = 1; j < 64; j <<= 1) {
            float ov = __shfl_xor(cvv, j, 64); int oi = __shfl_xor(cii, j, 64);
            bool ob = (ov > cvv) || (ov == cvv && oi < cii);
            if (ob) { cvv = ov; cii = oi; }
          }
          if (lane == 0) {
            int bb = cii / VV; int tok = cii - bb * VV;
            float4 st = lstat4[tok];
            s_scores[it] = cvv; s_last[it] = tok;
            s_lmm[it] = st.x; s_lmls[it] = st.y;
            s_toks[t * BEAMW + it] = (unsigned short)tok;
            s_bps[t * BEAMW + it] = (unsigned char)bb;
          }
          pv = cvv; pi = cii;
        }
      }
    }
    __syncthreads();
  }

  if (tid < BEAMW) {
    out[tid] = s_scores[tid];
    int ptr = tid;
    for (int t = TT - 1; t >= 0; --t) {
      int tok = (int)s_toks[t * BEAMW + ptr];
      out[BEAMW + tid * TT + t] = (float)tok;
      ptr = (int)s_bps[t * BEAMW + ptr];
    }
  }
}

extern "C" void kernel_launch(void* const* d_in, const int* in_sizes, int n_in,
                              void* d_out, int out_size, void* d_ws, size_t ws_size,
                              hipStream_t stream) {
  const float* asr = (const float*)d_in[0];
  const float* lm  = (const float*)d_in[1];
  float* out = (float*)d_out;
  float* ws  = (float*)d_ws;

  int build = (ws_size >= ws_need_floats() * sizeof(float)) ? 1 : 0;
  hipLaunchKernelGGL(prep_kernel, dim3(VV + TT), dim3(256), 0, stream, asr, lm, ws, build);
  if (build)
    hipLaunchKernelGGL(beam_fast, dim3(1), dim3(1024), 0, stream, asr, lm, ws, out);
  else
    hipLaunchKernelGGL(beam_slow, dim3(1), dim3(1024), 0, stream, asr, lm, ws, out);
}